// Round 1
// baseline (841.265 us; speedup 1.0000x reference)
//
#include <hip/hip_runtime.h>

// ES gradient for 2-layer MLP (D_IN=1024, HID=2048, D_OUT=10, POP=40, STD=0.1).
// Pipeline: k_base -> k_big (GEMM x@E1_p + fused layer-2 partial preds)
//           -> k_loss (80 losses) -> k_rank (centered ranks) -> k_grad.
// Output depends on losses ONLY through ranks => fp32 everywhere (rank-exact).

#define NPLL 2119690LL          // N_PARAMS
#define S1_  2097152            // W1 end
#define S2_  2099200            // b1 end
#define S3_  2119680            // W2 end

// ws layout (floats):
//   base : [0, 524288)                 base[j][b], j<2048, b<256 (x@W1+b1)
//   pp   : [524288, 524288+3276800)    partial preds [p][s][jt16][b256][o10]
//   loss : [3801088, 3801168)          80 losses [p][s]
//   g    : [3801168, 3801208)          40 pair coefficients
#define WS_PP   524288
#define WS_LOSS 3801088
#define WS_G    3801168

// ---------------- k_base: base[j][b] = (x @ W1)[b][j] + b1[j] ----------------
__global__ __launch_bounds__(256) void k_base(const float* __restrict__ x,
                                              const float* __restrict__ W1,
                                              const float* __restrict__ b1,
                                              float* __restrict__ base) {
  constexpr int STR = 72;
  __shared__ float xs[32 * STR];  // [k][b], b<32
  __shared__ float es[32 * STR];  // [k][j], j<64 (sub-padded every 32)
  const int t  = threadIdx.x;
  const int j0 = blockIdx.x * 64;
  const int b0 = blockIdx.y * 32;
  const int tj = t & 15;   // 16 j-groups of 4
  const int tb = t >> 4;   // 16 b-groups of 2
  float acc[4][2] = {};
  for (int k0 = 0; k0 < 1024; k0 += 32) {
    __syncthreads();
    {  // stage x tile: 32b x 32k = 256 float4, 1/thread
      int bb = t >> 3, kq = t & 7;
      float4 v = *(const float4*)&x[(size_t)(b0 + bb) * 1024 + k0 + kq * 4];
      int kb = kq * 4;
      xs[(kb + 0) * STR + bb] = v.x;
      xs[(kb + 1) * STR + bb] = v.y;
      xs[(kb + 2) * STR + bb] = v.z;
      xs[(kb + 3) * STR + bb] = v.w;
    }
#pragma unroll
    for (int r = 0; r < 2; ++r) {  // stage W1 tile: 32k x 64j = 512 float4
      int idx = t + r * 256;
      int k = idx >> 4, jq = idx & 15, col = jq * 4;
      float4 v = *(const float4*)&W1[(size_t)(k0 + k) * 2048 + j0 + col];
      *(float4*)&es[k * STR + col + 4 * (col >> 5)] = v;
    }
    __syncthreads();
#pragma unroll 8
    for (int k = 0; k < 32; ++k) {
      const int ce = tj * 4;
      float4 e = *(const float4*)&es[k * STR + ce + 4 * (ce >> 5)];
      float2 a = *(const float2*)&xs[k * STR + tb * 2];
      acc[0][0] += e.x * a.x; acc[0][1] += e.x * a.y;
      acc[1][0] += e.y * a.x; acc[1][1] += e.y * a.y;
      acc[2][0] += e.z * a.x; acc[2][1] += e.z * a.y;
      acc[3][0] += e.w * a.x; acc[3][1] += e.w * a.y;
    }
  }
#pragma unroll
  for (int jj = 0; jj < 4; ++jj) {
    int j = j0 + tj * 4 + jj;
    float bv = b1[j];
    float2 o = make_float2(acc[jj][0] + bv, acc[jj][1] + bv);
    *(float2*)&base[(size_t)j * 256 + b0 + tb * 2] = o;
  }
}

// ---------------- k_big: T = x @ E1_p tile, fused relu + layer-2 partials ----
__global__ __launch_bounds__(256) void k_big(const float* __restrict__ x,
                                             const float* __restrict__ noise,
                                             const float* __restrict__ W2,
                                             const float* __restrict__ base,
                                             float* __restrict__ pp) {
  constexpr int STR = 140;
  __shared__ float xs[32 * STR];  // [k][b], b<128 (sub-padded)
  __shared__ float es[32 * STR];  // [k][j], j<128 (sub-padded)
  const int t  = threadIdx.x;
  const int p  = blockIdx.x;       // pair 0..39
  const int jt = blockIdx.y;       // j-tile 0..15 (128 wide)
  const int bt = blockIdx.z;       // b-tile 0..1  (128 wide)
  const int j0 = jt * 128, b0 = bt * 128;
  const int tj = t & 15, tb = t >> 4;
  const int tj8 = tj * 8, tb8 = tb * 8;
  const int offE = tj8 + 4 * (tj8 >> 5);
  const int offA = tb8 + 4 * (tb8 >> 5);
  const size_t pN = (size_t)p * NPLL;
  const float* Bp = noise + pN;    // E1_p: [k*2048 + j]
  float acc[8][8] = {};

  for (int k0 = 0; k0 < 1024; k0 += 32) {
    __syncthreads();
#pragma unroll
    for (int r = 0; r < 4; ++r) {  // stage x: 128b x 32k = 1024 float4
      int idx = t + r * 256;
      int bb = idx >> 3, kq = idx & 7;
      float4 v = *(const float4*)&x[(size_t)(b0 + bb) * 1024 + k0 + kq * 4];
      int kb = kq * 4, wo = bb + 4 * (bb >> 5);
      xs[(kb + 0) * STR + wo] = v.x;
      xs[(kb + 1) * STR + wo] = v.y;
      xs[(kb + 2) * STR + wo] = v.z;
      xs[(kb + 3) * STR + wo] = v.w;
    }
#pragma unroll
    for (int r = 0; r < 8; ++r) {  // stage E1: 32k x 128j = 2048 float2
      // float2 (not float4): noise row base is only 8B-aligned (N_PARAMS*4 % 16 == 8)
      int idx = t + r * 256;
      int k = idx >> 6, jq = idx & 63, col = jq * 2;
      float2 v = *(const float2*)&Bp[(size_t)(k0 + k) * 2048 + j0 + col];
      *(float2*)&es[k * STR + col + 4 * (col >> 5)] = v;
    }
    __syncthreads();
#pragma unroll 4
    for (int k = 0; k < 32; ++k) {
      float4 e0 = *(const float4*)&es[k * STR + offE];
      float4 e1 = *(const float4*)&es[k * STR + offE + 4];
      float4 a0 = *(const float4*)&xs[k * STR + offA];
      float4 a1 = *(const float4*)&xs[k * STR + offA + 4];
      float ev[8] = {e0.x, e0.y, e0.z, e0.w, e1.x, e1.y, e1.z, e1.w};
      float av[8] = {a0.x, a0.y, a0.z, a0.w, a1.x, a1.y, a1.z, a1.w};
#pragma unroll
      for (int jj = 0; jj < 8; ++jj)
#pragma unroll
        for (int bb = 0; bb < 8; ++bb) acc[jj][bb] += ev[jj] * av[bb];
    }
  }

  // epilogue: h = relu(base + s*0.1*(T + e1)), partial pred over this j-tile
  float e1n[8];
#pragma unroll
  for (int q = 0; q < 4; ++q) {
    float2 v = *(const float2*)&noise[pN + S1_ + j0 + tj8 + q * 2];
    e1n[q * 2] = v.x;
    e1n[q * 2 + 1] = v.y;
  }
#pragma unroll 1
  for (int s = 0; s < 2; ++s) {
    const float sf = s ? -0.1f : 0.1f;
    float ppv[8][10];
#pragma unroll
    for (int bb = 0; bb < 8; ++bb)
#pragma unroll
      for (int o = 0; o < 10; ++o) ppv[bb][o] = 0.f;
#pragma unroll
    for (int jj = 0; jj < 8; ++jj) {
      const int j = j0 + tj8 + jj;
      float4 bs0 = *(const float4*)&base[(size_t)j * 256 + b0 + tb8];
      float4 bs1 = *(const float4*)&base[(size_t)j * 256 + b0 + tb8 + 4];
      float bv[8] = {bs0.x, bs0.y, bs0.z, bs0.w, bs1.x, bs1.y, bs1.z, bs1.w};
      float h[8];
#pragma unroll
      for (int bb = 0; bb < 8; ++bb) {
        float pre = bv[bb] + sf * (acc[jj][bb] + e1n[jj]);
        h[bb] = pre > 0.f ? pre : 0.f;
      }
#pragma unroll
      for (int o = 0; o < 10; ++o) {
        float w2s = W2[j * 10 + o] + sf * noise[pN + S2_ + (size_t)j * 10 + o];
#pragma unroll
        for (int bb = 0; bb < 8; ++bb) ppv[bb][o] += h[bb] * w2s;
      }
    }
    // reduce over tj (16 lanes within each wave quarter)
#pragma unroll
    for (int m = 1; m <= 8; m <<= 1)
#pragma unroll
      for (int bb = 0; bb < 8; ++bb)
#pragma unroll
        for (int o = 0; o < 10; ++o)
          ppv[bb][o] += __shfl_xor(ppv[bb][o], m, 64);
    if (tj == 0) {
#pragma unroll
      for (int bb = 0; bb < 8; ++bb)
#pragma unroll
        for (int o = 0; o < 10; ++o)
          pp[((((size_t)p * 2 + s) * 16 + jt) * 256 + (b0 + tb8 + bb)) * 10 + o] =
              ppv[bb][o];
    }
  }
}

// ---------------- k_loss: 80 losses ----------------
__global__ __launch_bounds__(256) void k_loss(const float* __restrict__ pp,
                                              const float* __restrict__ y,
                                              const float* __restrict__ b2,
                                              const float* __restrict__ noise,
                                              float* __restrict__ loss) {
  const int b = threadIdx.x;
  const int p = blockIdx.x >> 1, s = blockIdx.x & 1;
  const float sf = s ? -0.1f : 0.1f;
  const size_t pN = (size_t)p * NPLL;
  float pred[10];
#pragma unroll
  for (int o = 0; o < 10; ++o) pred[o] = b2[o] + sf * noise[pN + S3_ + o];
  for (int jt = 0; jt < 16; ++jt) {
    const float* src = &pp[((((size_t)p * 2 + s) * 16 + jt) * 256 + b) * 10];
#pragma unroll
    for (int o = 0; o < 10; ++o) pred[o] += src[o];
  }
  float e = 0.f;
#pragma unroll
  for (int o = 0; o < 10; ++o) {
    float d = pred[o] - y[b * 10 + o];
    e += d * d;
  }
  __shared__ float red[256];
  red[b] = e;
  __syncthreads();
  for (int st = 128; st > 0; st >>= 1) {
    if (b < st) red[b] += red[b + st];
    __syncthreads();
  }
  if (b == 0) loss[blockIdx.x] = red[0] * (1.0f / 2560.0f);
}

// ---------------- k_rank: stable centered ranks -> pair coefficients --------
__global__ void k_rank(const float* __restrict__ loss, float* __restrict__ g) {
  __shared__ float ls[80];
  __shared__ float rk[80];
  const int t = threadIdx.x;
  if (t < 80) ls[t] = loss[t];
  __syncthreads();
  if (t < 80) {
    float li = ls[t];
    int r = 0;
    for (int j = 0; j < 80; ++j) {
      float lj = ls[j];
      r += (lj < li) || (lj == li && j < t);  // stable tie-break = argsort
    }
    rk[t] = (float)r;
  }
  __syncthreads();
  if (t < 40) g[t] = (rk[2 * t] - rk[2 * t + 1]) * (1.0f / (79.0f * 40.0f));
}

// ---------------- k_grad: out[k] = sum_p noise[p][k] * g[p] -----------------
__global__ __launch_bounds__(256) void k_grad(const float* __restrict__ noise,
                                              const float* __restrict__ g,
                                              float* __restrict__ out) {
  __shared__ float gg[40];
  const int t = threadIdx.x;
  if (t < 40) gg[t] = g[t];
  __syncthreads();
  const long long NH = NPLL / 2;  // N_PARAMS even -> exact float2 coverage
  long long idx = (long long)blockIdx.x * 256 + t;
  if (idx >= NH) return;
  float2 a = make_float2(0.f, 0.f);
#pragma unroll 8
  for (int p = 0; p < 40; ++p) {
    float2 v = *(const float2*)&noise[(size_t)p * NPLL + idx * 2];
    a.x += v.x * gg[p];
    a.y += v.y * gg[p];
  }
  *(float2*)&out[idx * 2] = a;
}

extern "C" void kernel_launch(void* const* d_in, const int* in_sizes, int n_in,
                              void* d_out, int out_size, void* d_ws, size_t ws_size,
                              hipStream_t stream) {
  const float* x     = (const float*)d_in[0];
  const float* y     = (const float*)d_in[1];
  const float* W1    = (const float*)d_in[2];
  const float* b1    = (const float*)d_in[3];
  const float* W2    = (const float*)d_in[4];
  const float* b2    = (const float*)d_in[5];
  const float* noise = (const float*)d_in[6];
  float* out  = (float*)d_out;
  float* ws   = (float*)d_ws;   // needs ~15.3 MB
  float* base = ws;
  float* pp   = ws + WS_PP;
  float* loss = ws + WS_LOSS;
  float* g    = ws + WS_G;

  k_base<<<dim3(32, 8), 256, 0, stream>>>(x, W1, b1, base);
  k_big<<<dim3(40, 16, 2), 256, 0, stream>>>(x, noise, W2, base, pp);
  k_loss<<<80, 256, 0, stream>>>(pp, y, b2, noise, loss);
  k_rank<<<1, 128, 0, stream>>>(loss, g);
  k_grad<<<4141, 256, 0, stream>>>(noise, g, out);
}

// Round 3
// 390.652 us; speedup vs baseline: 2.1535x; 2.1535x over previous
//
#include <hip/hip_runtime.h>

// ES gradient for 2-layer MLP (D_IN=1024, HID=2048, D_OUT=10, POP=40, STD=0.1).
// k_base (fp32) -> k_big (split-f16 MFMA GEMM x@E1 + fused layer-2 partials)
// -> k_loss -> k_rank -> k_grad.
// Output depends on losses ONLY through ranks; split-f16 keeps loss error ~1e-5
// vs adjacent-rank gaps ~1e-2.

#define NPLL 2119690LL          // N_PARAMS
#define S1_  2097152            // W1 end
#define S2_  2099200            // b1 end
#define S3_  2119680            // W2 end

// ws layout (floats): base[2048][256] | pp[40][2][16][256][10] | loss[80] | g[40]
#define WS_PP   524288
#define WS_LOSS 3801088
#define WS_G    3801168

typedef _Float16 f16;
typedef __fp16   fp16x2 __attribute__((ext_vector_type(2)));
typedef _Float16 f16x8 __attribute__((ext_vector_type(8)));
typedef float    f32x4 __attribute__((ext_vector_type(4)));

__device__ __forceinline__ unsigned pk2r(float a, float b, float& ra, float& rb) {
  fp16x2 h = __builtin_amdgcn_cvt_pkrtz(a, b);   // v_cvt_pkrtz_f16_f32
  ra = a - (float)h[0];
  rb = b - (float)h[1];
  return __builtin_bit_cast(unsigned, h);
}
__device__ __forceinline__ unsigned pk2(float a, float b) {
  fp16x2 h = __builtin_amdgcn_cvt_pkrtz(a, b);
  return __builtin_bit_cast(unsigned, h);
}

// ---------------- k_base: base[j][b] = (x @ W1)[b][j] + b1[j] (fp32) --------
__global__ __launch_bounds__(256) void k_base(const float* __restrict__ x,
                                              const float* __restrict__ W1,
                                              const float* __restrict__ b1,
                                              float* __restrict__ base) {
  constexpr int STR = 72;
  __shared__ float xs[32 * STR];
  __shared__ float es[32 * STR];
  const int t  = threadIdx.x;
  const int j0 = blockIdx.x * 64;
  const int b0 = blockIdx.y * 32;
  const int tj = t & 15;
  const int tb = t >> 4;
  float acc[4][2] = {};
  for (int k0 = 0; k0 < 1024; k0 += 32) {
    __syncthreads();
    {
      int bb = t >> 3, kq = t & 7;
      float4 v = *(const float4*)&x[(size_t)(b0 + bb) * 1024 + k0 + kq * 4];
      int kb = kq * 4;
      xs[(kb + 0) * STR + bb] = v.x;
      xs[(kb + 1) * STR + bb] = v.y;
      xs[(kb + 2) * STR + bb] = v.z;
      xs[(kb + 3) * STR + bb] = v.w;
    }
#pragma unroll
    for (int r = 0; r < 2; ++r) {
      int idx = t + r * 256;
      int k = idx >> 4, jq = idx & 15, col = jq * 4;
      float4 v = *(const float4*)&W1[(size_t)(k0 + k) * 2048 + j0 + col];
      *(float4*)&es[k * STR + col + 4 * (col >> 5)] = v;
    }
    __syncthreads();
#pragma unroll 8
    for (int k = 0; k < 32; ++k) {
      const int ce = tj * 4;
      float4 e = *(const float4*)&es[k * STR + ce + 4 * (ce >> 5)];
      float2 a = *(const float2*)&xs[k * STR + tb * 2];
      acc[0][0] += e.x * a.x; acc[0][1] += e.x * a.y;
      acc[1][0] += e.y * a.x; acc[1][1] += e.y * a.y;
      acc[2][0] += e.z * a.x; acc[2][1] += e.z * a.y;
      acc[3][0] += e.w * a.x; acc[3][1] += e.w * a.y;
    }
  }
#pragma unroll
  for (int jj = 0; jj < 4; ++jj) {
    int j = j0 + tj * 4 + jj;
    float bv = b1[j];
    float2 o = make_float2(acc[jj][0] + bv, acc[jj][1] + bv);
    *(float2*)&base[(size_t)j * 256 + b0 + tb * 2] = o;
  }
}

// ---------------- k_big: split-f16 MFMA T = x@E1, fused epilogue ------------
// grid (80 = p*2+bt, 16 = jt), 256 threads = 4 waves, wave tile 64j x 64b.
#define ESTR 72   // f16 per LDS row: cols 0..31 hi(k), 32..63 lo(k), 8 pad
__global__ __launch_bounds__(256, 2) void k_big(const float* __restrict__ x,
                                                const float* __restrict__ noise,
                                                const float* __restrict__ W2,
                                                const float* __restrict__ base,
                                                float* __restrict__ pp) {
  __shared__ __align__(16) f16 eA[128 * ESTR];  // E^T tile [j][k-cols]
  __shared__ __align__(16) f16 xB[128 * ESTR];  // x tile [b][k-cols]
  __shared__ float w2l[1280], e2l[1280], e1l[128];
  __shared__ float red[1280];

  const int t    = threadIdx.x;
  const int p    = blockIdx.x >> 1, bt = blockIdx.x & 1, jt = blockIdx.y;
  const int j0   = jt * 128, b0 = bt * 128;
  const int wave = t >> 6, lane = t & 63;
  const int lm   = lane & 15, g8 = (lane >> 4) * 8;
  const int g4   = (lane >> 4) * 4;
  const int wj0  = (wave & 1) * 64, wb0 = (wave >> 1) * 64;
  const size_t pN = (size_t)p * NPLL;
  const int rl = t & 63;           // staging row (and row+64)
  const int kq = (t >> 6) * 8;     // staging k-offset within 32-k step

  // epilogue tables (visibility guaranteed by the k-loop barriers)
  for (int i = t; i < 1280; i += 256) {
    w2l[i] = W2[j0 * 10 + i];
    e2l[i] = noise[pN + S2_ + (size_t)j0 * 10 + i];
  }
  if (t < 128) e1l[t] = noise[pN + S1_ + j0 + t];

  float vE0[8], vE1[8], vX0[8], vX1[8];
  f32x4 acc[4][4];
#pragma unroll
  for (int a = 0; a < 4; ++a)
#pragma unroll
    for (int b = 0; b < 4; ++b) acc[a][b] = (f32x4){0.f, 0.f, 0.f, 0.f};

#define LOADK(K0)                                                              \
  do {                                                                         \
    const float* eg = &noise[pN + (size_t)((K0) + kq) * 2048 + j0 + rl];       \
    _Pragma("unroll") for (int d = 0; d < 8; ++d) {                            \
      vE0[d] = eg[(size_t)d * 2048];                                           \
      vE1[d] = eg[(size_t)d * 2048 + 64];                                      \
    }                                                                          \
    const float* xg = &x[(size_t)(b0 + rl) * 1024 + (K0) + kq];                \
    float4 a0 = *(const float4*)xg;                                            \
    float4 a1 = *(const float4*)(xg + 4);                                      \
    float4 c0 = *(const float4*)(xg + 65536);                                  \
    float4 c1 = *(const float4*)(xg + 65540);                                  \
    vX0[0] = a0.x; vX0[1] = a0.y; vX0[2] = a0.z; vX0[3] = a0.w;                \
    vX0[4] = a1.x; vX0[5] = a1.y; vX0[6] = a1.z; vX0[7] = a1.w;                \
    vX1[0] = c0.x; vX1[1] = c0.y; vX1[2] = c0.z; vX1[3] = c0.w;                \
    vX1[4] = c1.x; vX1[5] = c1.y; vX1[6] = c1.z; vX1[7] = c1.w;                \
  } while (0)

#define CVW(V, DST)                                                            \
  do {                                                                         \
    float r0, r1, r2, r3, r4, r5, r6, r7;                                      \
    uint4 H, L;                                                                \
    H.x = pk2r(V[0], V[1], r0, r1);                                            \
    H.y = pk2r(V[2], V[3], r2, r3);                                            \
    H.z = pk2r(V[4], V[5], r4, r5);                                            \
    H.w = pk2r(V[6], V[7], r6, r7);                                            \
    *(uint4*)(DST) = H;                                                        \
    L.x = pk2(r0, r1); L.y = pk2(r2, r3);                                      \
    L.z = pk2(r4, r5); L.w = pk2(r6, r7);                                      \
    *(uint4*)((DST) + 32) = L;                                                 \
  } while (0)

  LOADK(0);
  for (int ks = 0; ks < 32; ++ks) {
    __syncthreads();   // previous compute done; LDS free
    CVW(vE0, &eA[rl * ESTR + kq]);
    CVW(vE1, &eA[(rl + 64) * ESTR + kq]);
    CVW(vX0, &xB[rl * ESTR + kq]);
    CVW(vX1, &xB[(rl + 64) * ESTR + kq]);
    if (ks < 31) LOADK((ks + 1) * 32);   // prefetch next step into regs
    __syncthreads();   // tile ready
    f16x8 Ah[4], Al[4], Bh[4], Bl[4];
#pragma unroll
    for (int mf = 0; mf < 4; ++mf) {
      Ah[mf] = *(const f16x8*)&eA[(wj0 + mf * 16 + lm) * ESTR + g8];
      Al[mf] = *(const f16x8*)&eA[(wj0 + mf * 16 + lm) * ESTR + 32 + g8];
      Bh[mf] = *(const f16x8*)&xB[(wb0 + mf * 16 + lm) * ESTR + g8];
      Bl[mf] = *(const f16x8*)&xB[(wb0 + mf * 16 + lm) * ESTR + 32 + g8];
    }
#pragma unroll
    for (int mf = 0; mf < 4; ++mf)
#pragma unroll
      for (int nf = 0; nf < 4; ++nf) {
        acc[mf][nf] = __builtin_amdgcn_mfma_f32_16x16x32_f16(Ah[mf], Bh[nf], acc[mf][nf], 0, 0, 0);
        acc[mf][nf] = __builtin_amdgcn_mfma_f32_16x16x32_f16(Ah[mf], Bl[nf], acc[mf][nf], 0, 0, 0);
        acc[mf][nf] = __builtin_amdgcn_mfma_f32_16x16x32_f16(Al[mf], Bh[nf], acc[mf][nf], 0, 0, 0);
      }
  }

  // ---- epilogue: both signs in one pass over (j,b) ----
  float ppvP[4][10] = {};
  float ppvM[4][10] = {};
#pragma unroll
  for (int mf = 0; mf < 4; ++mf)
#pragma unroll
    for (int r = 0; r < 4; ++r) {
      const int jl = wj0 + mf * 16 + g4 + r;   // D row = (lane>>4)*4 + reg
      const float e1v = e1l[jl];
      float w2p[10], w2m[10];
#pragma unroll
      for (int o = 0; o < 10; ++o) {
        float w2 = w2l[jl * 10 + o], e2 = e2l[jl * 10 + o];
        w2p[o] = fmaf(0.1f, e2, w2);
        w2m[o] = fmaf(-0.1f, e2, w2);
      }
#pragma unroll
      for (int nf = 0; nf < 4; ++nf) {
        const int bl = wb0 + nf * 16 + lm;      // D col = lane&15
        const float bs = base[(size_t)(j0 + jl) * 256 + b0 + bl];
        const float tv = acc[mf][nf][r] + e1v;
        const float hp = fmaxf(fmaf(0.1f, tv, bs), 0.f);
        const float hm = fmaxf(fmaf(-0.1f, tv, bs), 0.f);
#pragma unroll
        for (int o = 0; o < 10; ++o) {
          ppvP[nf][o] = fmaf(hp, w2p[o], ppvP[nf][o]);
          ppvM[nf][o] = fmaf(hm, w2m[o], ppvM[nf][o]);
        }
      }
    }

  // cross-lane reduce over the 4 row-groups (lanes differing in bits 4,5)
#pragma unroll
  for (int nf = 0; nf < 4; ++nf)
#pragma unroll
    for (int o = 0; o < 10; ++o) {
      float v = ppvP[nf][o];
      v += __shfl_xor(v, 16, 64);
      v += __shfl_xor(v, 32, 64);
      ppvP[nf][o] = v;
      float u = ppvM[nf][o];
      u += __shfl_xor(u, 16, 64);
      u += __shfl_xor(u, 32, 64);
      ppvM[nf][o] = u;
    }

  const int wjh = wave & 1, wbh = wave >> 1;
  // s = 0 (+)
  __syncthreads();
  if (wjh == 1 && lane < 16) {
#pragma unroll
    for (int nf = 0; nf < 4; ++nf)
#pragma unroll
      for (int o = 0; o < 10; ++o)
        red[(wbh * 64 + nf * 16 + lane) * 10 + o] = ppvP[nf][o];
  }
  __syncthreads();
  if (wjh == 0 && lane < 16) {
#pragma unroll
    for (int nf = 0; nf < 4; ++nf) {
      const int bl = wbh * 64 + nf * 16 + lane;
#pragma unroll
      for (int o = 0; o < 10; ++o)
        pp[((((size_t)p * 2 + 0) * 16 + jt) * 256 + b0 + bl) * 10 + o] =
            ppvP[nf][o] + red[bl * 10 + o];
    }
  }
  __syncthreads();
  // s = 1 (-)
  if (wjh == 1 && lane < 16) {
#pragma unroll
    for (int nf = 0; nf < 4; ++nf)
#pragma unroll
      for (int o = 0; o < 10; ++o)
        red[(wbh * 64 + nf * 16 + lane) * 10 + o] = ppvM[nf][o];
  }
  __syncthreads();
  if (wjh == 0 && lane < 16) {
#pragma unroll
    for (int nf = 0; nf < 4; ++nf) {
      const int bl = wbh * 64 + nf * 16 + lane;
#pragma unroll
      for (int o = 0; o < 10; ++o)
        pp[((((size_t)p * 2 + 1) * 16 + jt) * 256 + b0 + bl) * 10 + o] =
            ppvM[nf][o] + red[bl * 10 + o];
    }
  }
#undef LOADK
#undef CVW
}

// ---------------- k_loss: 80 losses ----------------
__global__ __launch_bounds__(256) void k_loss(const float* __restrict__ pp,
                                              const float* __restrict__ y,
                                              const float* __restrict__ b2,
                                              const float* __restrict__ noise,
                                              float* __restrict__ loss) {
  const int b = threadIdx.x;
  const int p = blockIdx.x >> 1, s = blockIdx.x & 1;
  const float sf = s ? -0.1f : 0.1f;
  const size_t pN = (size_t)p * NPLL;
  float pred[10];
#pragma unroll
  for (int o = 0; o < 10; ++o) pred[o] = b2[o] + sf * noise[pN + S3_ + o];
  for (int jt = 0; jt < 16; ++jt) {
    const float* src = &pp[((((size_t)p * 2 + s) * 16 + jt) * 256 + b) * 10];
#pragma unroll
    for (int o = 0; o < 10; ++o) pred[o] += src[o];
  }
  float e = 0.f;
#pragma unroll
  for (int o = 0; o < 10; ++o) {
    float d = pred[o] - y[b * 10 + o];
    e += d * d;
  }
  __shared__ float red[256];
  red[b] = e;
  __syncthreads();
  for (int st = 128; st > 0; st >>= 1) {
    if (b < st) red[b] += red[b + st];
    __syncthreads();
  }
  if (b == 0) loss[blockIdx.x] = red[0] * (1.0f / 2560.0f);
}

// ---------------- k_rank: stable centered ranks -> pair coefficients --------
__global__ void k_rank(const float* __restrict__ loss, float* __restrict__ g) {
  __shared__ float ls[80];
  __shared__ float rk[80];
  const int t = threadIdx.x;
  if (t < 80) ls[t] = loss[t];
  __syncthreads();
  if (t < 80) {
    float li = ls[t];
    int r = 0;
    for (int j = 0; j < 80; ++j) {
      float lj = ls[j];
      r += (lj < li) || (lj == li && j < t);  // stable tie-break = argsort
    }
    rk[t] = (float)r;
  }
  __syncthreads();
  if (t < 40) g[t] = (rk[2 * t] - rk[2 * t + 1]) * (1.0f / (79.0f * 40.0f));
}

// ---------------- k_grad: out[k] = sum_p noise[p][k] * g[p] -----------------
__global__ __launch_bounds__(256) void k_grad(const float* __restrict__ noise,
                                              const float* __restrict__ g,
                                              float* __restrict__ out) {
  __shared__ float gg[40];
  const int t = threadIdx.x;
  if (t < 40) gg[t] = g[t];
  __syncthreads();
  const long long NH = NPLL / 2;
  long long idx = (long long)blockIdx.x * 256 + t;
  if (idx >= NH) return;
  float2 a = make_float2(0.f, 0.f);
#pragma unroll 8
  for (int p = 0; p < 40; ++p) {
    float2 v = *(const float2*)&noise[(size_t)p * NPLL + idx * 2];
    a.x += v.x * gg[p];
    a.y += v.y * gg[p];
  }
  *(float2*)&out[idx * 2] = a;
}

extern "C" void kernel_launch(void* const* d_in, const int* in_sizes, int n_in,
                              void* d_out, int out_size, void* d_ws, size_t ws_size,
                              hipStream_t stream) {
  const float* x     = (const float*)d_in[0];
  const float* y     = (const float*)d_in[1];
  const float* W1    = (const float*)d_in[2];
  const float* b1    = (const float*)d_in[3];
  const float* W2    = (const float*)d_in[4];
  const float* b2    = (const float*)d_in[5];
  const float* noise = (const float*)d_in[6];
  float* out  = (float*)d_out;
  float* ws   = (float*)d_ws;   // ~15.3 MB
  float* base = ws;
  float* pp   = ws + WS_PP;
  float* loss = ws + WS_LOSS;
  float* g    = ws + WS_G;

  k_base<<<dim3(32, 8), 256, 0, stream>>>(x, W1, b1, base);
  k_big<<<dim3(80, 16), 256, 0, stream>>>(x, noise, W2, base, pp);
  k_loss<<<80, 256, 0, stream>>>(pp, y, b2, noise, loss);
  k_rank<<<1, 128, 0, stream>>>(loss, g);
  k_grad<<<4141, 256, 0, stream>>>(noise, g, out);
}